// Round 1
// baseline (2592.754 us; speedup 1.0000x reference)
//
#include <hip/hip_runtime.h>

#define N 307
#define CIN 5
#define HID 16
#define KORD 6
#define LH 32
#define BATCH 512
#define NT 320

__device__ __forceinline__ float sigmoidf(float x) {
    return __fdividef(1.f, 1.f + __expf(-x));
}
__device__ __forceinline__ float ftanh(float x) {
    // tanh(x) = 1 - 2/(e^{2x}+1); safe at +-inf (no NaN)
    float e = __expf(2.f * x);
    return 1.f - __fdividef(2.f, e + 1.f);
}

// ---------------- graph setup ----------------
__global__ __launch_bounds__(NT) void k_cosine(const float* __restrict__ E,
                                               float* __restrict__ G,
                                               float* __restrict__ dinv) {
    __shared__ float Es[N * 10];
    __shared__ float ninv[N];
    __shared__ float red[NT / 64];
    const int n = blockIdx.x, t = threadIdx.x;
    for (int i = t; i < N * 10; i += NT) Es[i] = E[i];
    __syncthreads();
    for (int r = t; r < N; r += NT) {
        float s = 0.f;
        for (int j = 0; j < 10; j++) { float v = Es[r * 10 + j]; s += v * v; }
        ninv[r] = rsqrtf(s);
    }
    __syncthreads();
    float gval = 0.f;
    if (t < N) {
        float s = 0.f;
        for (int j = 0; j < 10; j++) s += Es[n * 10 + j] * Es[t * 10 + j];
        gval = s * ninv[n] * ninv[t];
        G[n * N + t] = gval;
    }
    float v = gval;
    for (int off = 32; off; off >>= 1) v += __shfl_down(v, off);
    if ((t & 63) == 0) red[t >> 6] = v;
    __syncthreads();
    if (t == 0) {
        float s = 0.f;
        for (int w = 0; w < NT / 64; w++) s += red[w];
        dinv[n] = rsqrtf(s);
    }
}

__global__ __launch_bounds__(NT) void k_laplacian(const float* __restrict__ G,
                                                  const float* __restrict__ dinv,
                                                  float* __restrict__ polys) {
    const int n = blockIdx.x, t = threadIdx.x;
    if (t < N) {
        float eye = (t == n) ? 1.f : 0.f;
        float l = eye - dinv[n] * G[n * N + t] * dinv[t];
        polys[0 * N * N + n * N + t] = eye;
        polys[1 * N * N + n * N + t] = l;
    }
}

__global__ __launch_bounds__(NT) void k_cheb_step(float* __restrict__ polys, int k) {
    __shared__ float Lrow[N];
    const int n = blockIdx.x, t = threadIdx.x;
    const float* L = polys + 1 * N * N;
    for (int i = t; i < N; i += NT) Lrow[i] = L[n * N + i];
    __syncthreads();
    if (t < N) {
        const float* Tprev = polys + (size_t)(k - 1) * N * N;
        float acc = -polys[(size_t)(k - 2) * N * N + n * N + t];
        for (int m = 0; m < N; m++) acc = fmaf(2.f * Lrow[m], Tprev[m * N + t], acc);
        polys[(size_t)k * N * N + n * N + t] = acc;
    }
}

// ---------------- init: out0 = x@cou_w ; output = cheb ----------------
__global__ __launch_bounds__(NT) void k_init(const float* __restrict__ x,
                                             const float* __restrict__ polys,
                                             const float* __restrict__ cheb_w,
                                             const float* __restrict__ cheb_b,
                                             const float* __restrict__ cou_w,
                                             float* __restrict__ outA,
                                             float* __restrict__ outB) {
    __shared__ float xs[N * CIN];
    __shared__ float ws[KORD * CIN * HID];
    __shared__ float cw[CIN * HID];
    __shared__ float cb[HID];
    const int b = blockIdx.x, t = threadIdx.x;
    for (int i = t; i < N * CIN; i += NT) xs[i] = x[(size_t)b * N * CIN + i];
    for (int i = t; i < KORD * CIN * HID; i += NT) ws[i] = cheb_w[i];
    for (int i = t; i < CIN * HID; i += NT) cw[i] = cou_w[i];
    for (int i = t; i < HID; i += NT) cb[i] = cheb_b[i];
    __syncthreads();
    const int n = t;
    if (n < N) {
        float acc[HID];
        #pragma unroll
        for (int h = 0; h < HID; h++) {
            float s = 0.f;
            #pragma unroll
            for (int c = 0; c < CIN; c++) s = fmaf(xs[n * CIN + c], cw[c * HID + h], s);
            acc[h] = s;
        }
        float* oA = outA + (size_t)(b * N + n) * HID;
        #pragma unroll
        for (int h = 0; h < HID; h++) oA[h] = acc[h];

        #pragma unroll
        for (int h = 0; h < HID; h++) acc[h] = cb[h];
        for (int k = 0; k < KORD; k++) {
            float hk[CIN] = {0.f, 0.f, 0.f, 0.f, 0.f};
            const float* Prow = polys + (size_t)k * N * N + (size_t)n * N;
            for (int m = 0; m < N; m++) {
                float p = Prow[m];
                #pragma unroll
                for (int c = 0; c < CIN; c++) hk[c] = fmaf(p, xs[m * CIN + c], hk[c]);
            }
            #pragma unroll
            for (int c = 0; c < CIN; c++) {
                float hv = hk[c];
                const float* wrow = ws + (k * CIN + c) * HID;
                #pragma unroll
                for (int h = 0; h < HID; h++) acc[h] = fmaf(hv, wrow[h], acc[h]);
            }
        }
        float* oB = outB + (size_t)(b * N + n) * HID;
        #pragma unroll
        for (int h = 0; h < HID; h++) oB[h] = acc[h];
    }
}

// ---------------- GL ----------------
// MODE 0: out1 = t = GL(din); out2 = aux + 2t   (aux = prev2)
// MODE 1: out1 = aux + 0.5*tbuf + 0.5*GL(din)   (aux = cur)
template <int MODE>
__global__ __launch_bounds__(NT) void k_GL(
    const float* __restrict__ L,
    const float* __restrict__ din, int dstride,
    const float* __restrict__ aux, int astride,
    const float* __restrict__ tbuf,
    float* __restrict__ out1, int ostride,
    float* __restrict__ out2,
    const float* __restrict__ wo_g, const float* __restrict__ wf_g,
    const float* __restrict__ wt_g, const float* __restrict__ bt_g) {
    __shared__ float ds[N * HID];
    __shared__ float wo[HID * HID], wf[HID * HID], wt[HID * HID], bt[HID];
    const int b = blockIdx.x, t = threadIdx.x;
    for (int i = t; i < N * HID; i += NT) {
        int nn = i >> 4, h = i & 15;
        ds[i] = din[(size_t)(b * N + nn) * dstride + h];
    }
    for (int i = t; i < HID * HID; i += NT) { wo[i] = wo_g[i]; wf[i] = wf_g[i]; wt[i] = wt_g[i]; }
    for (int i = t; i < HID; i += NT) bt[i] = bt_g[i];
    __syncthreads();
    const int n = t;
    if (n < N) {
        float x[HID];
        #pragma unroll
        for (int h = 0; h < HID; h++) x[h] = ds[n * HID + h];
        float o1[HID] = {};
        const float* Lrow = L + (size_t)n * N;
        for (int m = 0; m < N; m++) {
            float lv = Lrow[m];
            #pragma unroll
            for (int h = 0; h < HID; h++) o1[h] = fmaf(lv, ds[m * HID + h], o1[h]);
        }
        // o3 = tanh(tanh(x@wo)@wf)
        float y[HID] = {};
        #pragma unroll
        for (int h2 = 0; h2 < HID; h2++) {
            float xv = x[h2];
            #pragma unroll
            for (int h = 0; h < HID; h++) y[h] = fmaf(xv, wo[h2 * HID + h], y[h]);
        }
        #pragma unroll
        for (int h = 0; h < HID; h++) y[h] = ftanh(y[h]);
        float y2[HID] = {};
        #pragma unroll
        for (int h2 = 0; h2 < HID; h2++) {
            float xv = y[h2];
            #pragma unroll
            for (int h = 0; h < HID; h++) y2[h] = fmaf(xv, wf[h2 * HID + h], y2[h]);
        }
        // z = (o1 - tanh(y2)) @ wt + bt
        float z[HID];
        #pragma unroll
        for (int h = 0; h < HID; h++) z[h] = bt[h];
        #pragma unroll
        for (int h2 = 0; h2 < HID; h2++) {
            float v = o1[h2] - ftanh(y2[h2]);
            #pragma unroll
            for (int h = 0; h < HID; h++) z[h] = fmaf(v, wt[h2 * HID + h], z[h]);
        }
        if (MODE == 0) {
            float* o1p = out1 + (size_t)(b * N + n) * ostride;
            const float* ap = aux + (size_t)(b * N + n) * astride;
            float* o2p = out2 + (size_t)(b * N + n) * HID;
            #pragma unroll
            for (int h = 0; h < HID; h++) {
                o1p[h] = z[h];
                o2p[h] = fmaf(2.f, z[h], ap[h]);
            }
        } else {
            const float* ap = aux + (size_t)(b * N + n) * astride;
            const float* tp = tbuf + (size_t)(b * N + n) * HID;
            float* o1p = out1 + (size_t)(b * N + n) * ostride;
            #pragma unroll
            for (int h = 0; h < HID; h++)
                o1p[h] = ap[h] + 0.5f * tp[h] + 0.5f * z[h];
        }
    }
}

// ---------------- NL ----------------
// MODE 0: out1 = t = NL(din); out2 = aux + 2t     (aux = prev2/step_00)
// MODE 1: out1 = aux + 0.5*tbuf + 0.5*NL(din)     (aux = base)
template <int MODE>
__global__ __launch_bounds__(NT) void k_NL(
    const float* __restrict__ din, int dstride,
    const float* __restrict__ aux, int astride,
    const float* __restrict__ tbuf,
    float* __restrict__ out1, int ostride,
    float* __restrict__ out2,
    const float* __restrict__ Wih, const float* __restrict__ bih,
    const float* __restrict__ w2) {
    __shared__ float WiT[LH * HID], WgT[LH * HID], WoT[LH * HID], w2s[LH * HID];
    __shared__ float bs[4 * LH];
    const int b = blockIdx.x, t = threadIdx.x;
    for (int i = t; i < LH * HID; i += NT) {
        int j = i >> 4, h = i & 15;
        WiT[i] = Wih[h * 4 * LH + j];
        WgT[i] = Wih[h * 4 * LH + 2 * LH + j];
        WoT[i] = Wih[h * 4 * LH + 3 * LH + j];
        w2s[i] = w2[i];
    }
    for (int i = t; i < 4 * LH; i += NT) bs[i] = bih[i];
    __syncthreads();
    const int n = t;
    if (n < N) {
        float x[HID];
        const float* dp = din + (size_t)(b * N + n) * dstride;
        #pragma unroll
        for (int h = 0; h < HID; h++) x[h] = dp[h];
        float acc[HID] = {};
        for (int j = 0; j < LH; j++) {
            float gi = bs[j], gg = bs[2 * LH + j], go = bs[3 * LH + j];
            #pragma unroll
            for (int h = 0; h < HID; h++) {
                float xv = x[h];
                gi = fmaf(xv, WiT[j * HID + h], gi);
                gg = fmaf(xv, WgT[j * HID + h], gg);
                go = fmaf(xv, WoT[j * HID + h], go);
            }
            float c = sigmoidf(gi) * ftanh(gg);
            float hh = sigmoidf(go) * ftanh(c);
            float th = ftanh(hh);
            #pragma unroll
            for (int h = 0; h < HID; h++) acc[h] = fmaf(th, w2s[j * HID + h], acc[h]);
        }
        if (MODE == 0) {
            float* o1p = out1 + (size_t)(b * N + n) * ostride;
            const float* ap = aux + (size_t)(b * N + n) * astride;
            float* o2p = out2 + (size_t)(b * N + n) * HID;
            #pragma unroll
            for (int h = 0; h < HID; h++) {
                o1p[h] = acc[h];
                o2p[h] = fmaf(2.f, acc[h], ap[h]);
            }
        } else {
            const float* ap = aux + (size_t)(b * N + n) * astride;
            const float* tp = tbuf + (size_t)(b * N + n) * HID;
            float* o1p = out1 + (size_t)(b * N + n) * ostride;
            #pragma unroll
            for (int h = 0; h < HID; h++)
                o1p[h] = ap[h] + 0.5f * tp[h] + 0.5f * acc[h];
        }
    }
}

// ---------------- step_00 / step_11 ----------------
__global__ __launch_bounds__(NT) void k_cstep(
    const float* __restrict__ X, const float* __restrict__ Y,
    float* __restrict__ X00, float* __restrict__ Z11,
    const float* __restrict__ cw_g, const float* __restrict__ cb_g,
    const float* __restrict__ c1w_g, const float* __restrict__ c1b_g) {
    __shared__ float cw[HID * HID], c1w[HID * HID], cb[HID], c1b[HID];
    const int b = blockIdx.x, t = threadIdx.x;
    for (int i = t; i < HID * HID; i += NT) { cw[i] = cw_g[i]; c1w[i] = c1w_g[i]; }
    for (int i = t; i < HID; i += NT) { cb[i] = cb_g[i]; c1b[i] = c1b_g[i]; }
    __syncthreads();
    const int n = t;
    if (n < N) {
        float a[HID], b2[HID];
        const float* xr = X + (size_t)(b * N + n) * HID;
        const float* yr = Y + (size_t)(b * N + n) * HID;
        #pragma unroll
        for (int h = 0; h < HID; h++) { a[h] = xr[h]; b2[h] = yr[h]; }
        float s0[HID], s1[HID];
        #pragma unroll
        for (int h = 0; h < HID; h++) { s0[h] = cb[h]; s1[h] = c1b[h]; }
        #pragma unroll
        for (int h2 = 0; h2 < HID; h2++) {
            float av = a[h2], bv = b2[h2];
            #pragma unroll
            for (int h = 0; h < HID; h++) {
                s0[h] = fmaf(av, cw[h2 * HID + h], s0[h]);
                s1[h] = fmaf(bv, c1w[h2 * HID + h], s1[h]);
            }
        }
        float* o0 = X00 + (size_t)(b * N + n) * HID;
        float* o1 = Z11 + (size_t)(b * N + n) * HID;
        #pragma unroll
        for (int h = 0; h < HID; h++) { o0[h] = s0[h]; o1[h] = s1[h]; }
    }
}

extern "C" void kernel_launch(void* const* d_in, const int* in_sizes, int n_in,
                              void* d_out, int out_size, void* d_ws, size_t ws_size,
                              hipStream_t stream) {
    const float* flow   = (const float*)d_in[0];
    const float* emb    = (const float*)d_in[1];
    const float* cheb_w = (const float*)d_in[2];
    const float* cheb_b = (const float*)d_in[3];
    const float* cou_w  = (const float*)d_in[4];
    const float* gl_out = (const float*)d_in[5];
    const float* gl_fk  = (const float*)d_in[6];
    const float* gl_tzw = (const float*)d_in[7];
    const float* gl_tzb = (const float*)d_in[8];
    const float* Wih    = (const float*)d_in[9];
    const float* lb     = (const float*)d_in[10];
    const float* w2     = (const float*)d_in[11];
    const float* c_w    = (const float*)d_in[12];
    const float* c_b    = (const float*)d_in[13];
    const float* c1_w   = (const float*)d_in[14];
    const float* c1_b   = (const float*)d_in[15];
    float* out = (float*)d_out;
    float* ws  = (float*)d_ws;

    size_t off = 0;
    float* polys = ws;            off += (size_t)KORD * N * N; off = (off + 255) & ~(size_t)255;
    float* G     = ws + off;      off += (size_t)N * N;        off = (off + 255) & ~(size_t)255;
    float* dinv  = ws + off;      off += 512;
    const size_t BNH = (size_t)BATCH * N * HID;
    float* X   = ws + off; off += BNH;
    float* Y   = ws + off; off += BNH;
    float* T   = ws + off; off += BNH;
    float* TMP = ws + off; off += BNH;
    float* Z   = ws + off; off += BNH;
    const float* L = polys + N * N;

    k_cosine<<<N, NT, 0, stream>>>(emb, G, dinv);
    k_laplacian<<<N, NT, 0, stream>>>(G, dinv, polys);
    for (int k = 2; k < KORD; k++)
        k_cheb_step<<<N, NT, 0, stream>>>(polys, k);
    k_init<<<BATCH, NT, 0, stream>>>(flow, polys, cheb_w, cheb_b, cou_w, X, Y);

    // GL chain: prev2 = X (out0), cur = Y (cheb output)
    for (int it = 0; it < 10; it++) {
        k_GL<0><<<BATCH, NT, 0, stream>>>(L, Y, HID, X, HID, nullptr, T, HID, TMP,
                                          gl_out, gl_fk, gl_tzw, gl_tzb);
        k_GL<1><<<BATCH, NT, 0, stream>>>(L, TMP, HID, Y, HID, T, X, HID, nullptr,
                                          gl_out, gl_fk, gl_tzw, gl_tzb);
        float* sw = X; X = Y; Y = sw;  // prev2 = old cur, cur = new
    }
    // X = step_0, Y = step_1
    k_cstep<<<BATCH, NT, 0, stream>>>(X, Y, X, Z, c_w, c_b, c1_w, c1_b);
    // X = step_00, Y = step_1, Z = step_11

    // NL iter 0: t = NL(step_11); tmp = step_00 + 2t; g0 = 0.5t + step_1 + 0.5*NL(tmp)
    k_NL<0><<<BATCH, NT, 0, stream>>>(Z, HID, X, HID, nullptr, T, HID, TMP, Wih, lb, w2);
    k_NL<1><<<BATCH, NT, 0, stream>>>(TMP, HID, Y, HID, T, out + 0, 10 * HID, nullptr, Wih, lb, w2);
    // NL iter 1: prev2 = step_11 (Z)
    k_NL<0><<<BATCH, NT, 0, stream>>>(out + 0, 10 * HID, Z, HID, nullptr, T, HID, TMP, Wih, lb, w2);
    k_NL<1><<<BATCH, NT, 0, stream>>>(TMP, HID, out + 0, 10 * HID, T, out + HID, 10 * HID, nullptr, Wih, lb, w2);
    // NL iters 2..9
    for (int i = 2; i < 10; i++) {
        k_NL<0><<<BATCH, NT, 0, stream>>>(out + (i - 1) * HID, 10 * HID,
                                          out + (i - 2) * HID, 10 * HID, nullptr,
                                          T, HID, TMP, Wih, lb, w2);
        k_NL<1><<<BATCH, NT, 0, stream>>>(TMP, HID, out + (i - 1) * HID, 10 * HID, T,
                                          out + i * HID, 10 * HID, nullptr, Wih, lb, w2);
    }
}

// Round 3
// 1934.948 us; speedup vs baseline: 1.3400x; 1.3400x over previous
//
#include <hip/hip_runtime.h>

#define N 307
#define CIN 5
#define HID 16
#define KORD 6
#define LH 32
#define BATCH 512
#define NT 320
#define NTC 640

__device__ __forceinline__ float sigmoidf(float x) {
    return __fdividef(1.f, 1.f + __expf(-x));
}
__device__ __forceinline__ float ftanh(float x) {
    float e = __expf(2.f * x);
    return 1.f - __fdividef(2.f, e + 1.f);
}

// ---------------- graph setup ----------------
__global__ __launch_bounds__(NT) void k_cosine(const float* __restrict__ E,
                                               float* __restrict__ G,
                                               float* __restrict__ dinv) {
    __shared__ float Es[N * 10];
    __shared__ float ninv[N];
    __shared__ float red[NT / 64];
    const int n = blockIdx.x, t = threadIdx.x;
    for (int i = t; i < N * 10; i += NT) Es[i] = E[i];
    __syncthreads();
    for (int r = t; r < N; r += NT) {
        float s = 0.f;
        for (int j = 0; j < 10; j++) { float v = Es[r * 10 + j]; s += v * v; }
        ninv[r] = rsqrtf(s);
    }
    __syncthreads();
    float gval = 0.f;
    if (t < N) {
        float s = 0.f;
        for (int j = 0; j < 10; j++) s += Es[n * 10 + j] * Es[t * 10 + j];
        gval = s * ninv[n] * ninv[t];
        G[n * N + t] = gval;
    }
    float v = gval;
    for (int off = 32; off; off >>= 1) v += __shfl_down(v, off);
    if ((t & 63) == 0) red[t >> 6] = v;
    __syncthreads();
    if (t == 0) {
        float s = 0.f;
        for (int w = 0; w < NT / 64; w++) s += red[w];
        dinv[n] = rsqrtf(s);
    }
}

__global__ __launch_bounds__(NT) void k_laplacian(const float* __restrict__ G,
                                                  const float* __restrict__ dinv,
                                                  float* __restrict__ polys) {
    const int n = blockIdx.x, t = threadIdx.x;
    if (t < N) {
        float eye = (t == n) ? 1.f : 0.f;
        float l = eye - dinv[n] * G[n * N + t] * dinv[t];
        polys[0 * N * N + n * N + t] = eye;
        polys[1 * N * N + n * N + t] = l;
    }
}

__global__ __launch_bounds__(NT) void k_cheb_step(float* __restrict__ polys, int k) {
    __shared__ float Lrow[N];
    const int n = blockIdx.x, t = threadIdx.x;
    const float* L = polys + 1 * N * N;
    for (int i = t; i < N; i += NT) Lrow[i] = L[n * N + i];
    __syncthreads();
    if (t < N) {
        const float* Tprev = polys + (size_t)(k - 1) * N * N;
        float acc = -polys[(size_t)(k - 2) * N * N + n * N + t];
        for (int m = 0; m < N; m++) acc = fmaf(2.f * Lrow[m], Tprev[m * N + t], acc);
        polys[(size_t)k * N * N + n * N + t] = acc;
    }
}

// ---------------- GL evaluation (device fn) ----------------
// z = GL(v) where v is in LDS (bufh, row-major [N][16]) and x = v[n,:] in regs.
// o1 uses symmetry: L[n,m] == L[m,n]  ->  read L[m*N+n] (coalesced across lanes).
__device__ __forceinline__ void gl_eval(const float* __restrict__ L, int n,
                                        const float* __restrict__ bufh,
                                        const float x[HID],
                                        const float* __restrict__ woS,
                                        const float* __restrict__ wfS,
                                        const float* __restrict__ wtS,
                                        const float* __restrict__ btS,
                                        float z[HID]) {
    float o1[HID] = {};
    const float* pL = L + n;
    #pragma unroll 4
    for (int m = 0; m < N; m++) {
        float lv = pL[(size_t)m * N];
        const float4* r = (const float4*)(bufh + m * HID);
        float4 a = r[0], b4 = r[1], c4 = r[2], d4 = r[3];
        o1[0]  = fmaf(lv, a.x, o1[0]);  o1[1]  = fmaf(lv, a.y, o1[1]);
        o1[2]  = fmaf(lv, a.z, o1[2]);  o1[3]  = fmaf(lv, a.w, o1[3]);
        o1[4]  = fmaf(lv, b4.x, o1[4]); o1[5]  = fmaf(lv, b4.y, o1[5]);
        o1[6]  = fmaf(lv, b4.z, o1[6]); o1[7]  = fmaf(lv, b4.w, o1[7]);
        o1[8]  = fmaf(lv, c4.x, o1[8]); o1[9]  = fmaf(lv, c4.y, o1[9]);
        o1[10] = fmaf(lv, c4.z, o1[10]);o1[11] = fmaf(lv, c4.w, o1[11]);
        o1[12] = fmaf(lv, d4.x, o1[12]);o1[13] = fmaf(lv, d4.y, o1[13]);
        o1[14] = fmaf(lv, d4.z, o1[14]);o1[15] = fmaf(lv, d4.w, o1[15]);
    }
    // o3 = tanh(tanh(x@wo)@wf)
    float y[HID] = {};
    #pragma unroll
    for (int h2 = 0; h2 < HID; h2++) {
        float xv = x[h2];
        #pragma unroll
        for (int h = 0; h < HID; h++) y[h] = fmaf(xv, woS[h2 * HID + h], y[h]);
    }
    #pragma unroll
    for (int h = 0; h < HID; h++) y[h] = ftanh(y[h]);
    float y2[HID] = {};
    #pragma unroll
    for (int h2 = 0; h2 < HID; h2++) {
        float xv = y[h2];
        #pragma unroll
        for (int h = 0; h < HID; h++) y2[h] = fmaf(xv, wfS[h2 * HID + h], y2[h]);
    }
    #pragma unroll
    for (int h = 0; h < HID; h++) z[h] = btS[h];
    #pragma unroll
    for (int h2 = 0; h2 < HID; h2++) {
        float v = o1[h2] - ftanh(y2[h2]);
        #pragma unroll
        for (int h = 0; h < HID; h++) z[h] = fmaf(v, wtS[h2 * HID + h], z[h]);
    }
}

// ---------------- NL evaluation (device fn) ----------------
__device__ __forceinline__ void nl_eval(const float x[HID],
                                        const float* __restrict__ WiT,
                                        const float* __restrict__ WgT,
                                        const float* __restrict__ WoT,
                                        const float* __restrict__ w2S,
                                        const float* __restrict__ bS,
                                        float outv[HID]) {
    #pragma unroll
    for (int h = 0; h < HID; h++) outv[h] = 0.f;
    for (int j = 0; j < LH; j++) {
        float gi = bS[j], gg = bS[2 * LH + j], go = bS[3 * LH + j];
        const float4* wi = (const float4*)(WiT + j * HID);
        const float4* wg = (const float4*)(WgT + j * HID);
        const float4* wo4 = (const float4*)(WoT + j * HID);
        #pragma unroll
        for (int q = 0; q < 4; q++) {
            float4 a = wi[q], bb = wg[q], cc = wo4[q];
            gi = fmaf(x[4*q+0], a.x, gi); gi = fmaf(x[4*q+1], a.y, gi);
            gi = fmaf(x[4*q+2], a.z, gi); gi = fmaf(x[4*q+3], a.w, gi);
            gg = fmaf(x[4*q+0], bb.x, gg); gg = fmaf(x[4*q+1], bb.y, gg);
            gg = fmaf(x[4*q+2], bb.z, gg); gg = fmaf(x[4*q+3], bb.w, gg);
            go = fmaf(x[4*q+0], cc.x, go); go = fmaf(x[4*q+1], cc.y, go);
            go = fmaf(x[4*q+2], cc.z, go); go = fmaf(x[4*q+3], cc.w, go);
        }
        float c = sigmoidf(gi) * ftanh(gg);
        float hh = sigmoidf(go) * ftanh(c);
        float th = ftanh(hh);
        const float4* w2r = (const float4*)(w2S + j * HID);
        #pragma unroll
        for (int q = 0; q < 4; q++) {
            float4 a = w2r[q];
            outv[4*q+0] = fmaf(th, a.x, outv[4*q+0]);
            outv[4*q+1] = fmaf(th, a.y, outv[4*q+1]);
            outv[4*q+2] = fmaf(th, a.z, outv[4*q+2]);
            outv[4*q+3] = fmaf(th, a.w, outv[4*q+3]);
        }
    }
}

// ---------------- fused chain: init + 10x GL + cstep + 10x NL ----------------
__global__ __launch_bounds__(NTC, 3) void k_chain(
    const float* __restrict__ flow,
    const float* __restrict__ polys,
    const float* __restrict__ cheb_w, const float* __restrict__ cheb_b,
    const float* __restrict__ cou_w,
    const float* __restrict__ gl_wo, const float* __restrict__ gl_wf,
    const float* __restrict__ gl_wt, const float* __restrict__ gl_bt,
    const float* __restrict__ Wih, const float* __restrict__ bih,
    const float* __restrict__ w2,
    const float* __restrict__ c_w, const float* __restrict__ c_b,
    const float* __restrict__ c1_w, const float* __restrict__ c1_b,
    float* __restrict__ out) {
    __shared__ float buf[2][N * HID];
    __shared__ float woS[256], wfS[256], wtS[256], btS[16];
    __shared__ float cwS[256], c1wS[256], cbS[16], c1bS[16];
    __shared__ float WiT[LH * HID], WgT[LH * HID], WoT[LH * HID], w2S[LH * HID], bS[4 * LH];
    __shared__ float chebS[KORD * CIN * HID], chebBS[16], couS[CIN * HID];

    const int t = threadIdx.x;
    const int half = t / 320;
    const int n = t - half * 320;
    const int b = blockIdx.x * 2 + half;
    const float* L = polys + N * N;

    for (int i = t; i < 256; i += NTC) {
        woS[i] = gl_wo[i]; wfS[i] = gl_wf[i]; wtS[i] = gl_wt[i];
        cwS[i] = c_w[i]; c1wS[i] = c1_w[i];
    }
    for (int i = t; i < LH * HID; i += NTC) {
        int j = i >> 4, h = i & 15;
        WiT[i] = Wih[h * 4 * LH + j];
        WgT[i] = Wih[h * 4 * LH + 2 * LH + j];
        WoT[i] = Wih[h * 4 * LH + 3 * LH + j];
        w2S[i] = w2[i];
    }
    for (int i = t; i < 4 * LH; i += NTC) bS[i] = bih[i];
    for (int i = t; i < KORD * CIN * HID; i += NTC) chebS[i] = cheb_w[i];
    for (int i = t; i < HID; i += NTC) {
        btS[i] = gl_bt[i]; cbS[i] = c_b[i]; c1bS[i] = c1_b[i]; chebBS[i] = cheb_b[i];
    }
    for (int i = t; i < CIN * HID; i += NTC) couS[i] = cou_w[i];
    // stage this half's x into its buf region, padded to stride 8
    {
        float* xsh = buf[half];
        for (int i = n; i < N * CIN; i += 320) {
            int nn = i / CIN, c = i - nn * CIN;
            xsh[nn * 8 + c] = flow[(size_t)b * N * CIN + i];
        }
    }
    __syncthreads();

    float prev2[HID], cur[HID];
    // ---- init: prev2 = x@cou_w ; cur = cheb output ----
    if (n < N) {
        const float* xsh = buf[half];
        float xv[CIN];
        #pragma unroll
        for (int c = 0; c < CIN; c++) xv[c] = xsh[n * 8 + c];
        #pragma unroll
        for (int h = 0; h < HID; h++) {
            float s = 0.f;
            #pragma unroll
            for (int c = 0; c < CIN; c++) s = fmaf(xv[c], couS[c * HID + h], s);
            prev2[h] = s;
            cur[h] = chebBS[h];
        }
        for (int k = 0; k < KORD; k++) {
            const float* P = polys + (size_t)k * N * N + n;  // symmetric: col n == row n
            float hk[CIN] = {};
            #pragma unroll 4
            for (int m = 0; m < N; m++) {
                float p = P[(size_t)m * N];
                #pragma unroll
                for (int c = 0; c < CIN; c++) hk[c] = fmaf(p, xsh[m * 8 + c], hk[c]);
            }
            #pragma unroll
            for (int c = 0; c < CIN; c++) {
                float hv = hk[c];
                #pragma unroll
                for (int h = 0; h < HID; h++)
                    cur[h] = fmaf(hv, chebS[(k * CIN + c) * HID + h], cur[h]);
            }
        }
    }
    __syncthreads();  // xs region reads done; buf now free for GL ping buffer

    float* bufh = buf[half];
    // ---- GL chain ----
    for (int it = 0; it < 10; it++) {
        if (n < N) {
            float4* w = (float4*)(bufh + n * HID);
            w[0] = make_float4(cur[0], cur[1], cur[2], cur[3]);
            w[1] = make_float4(cur[4], cur[5], cur[6], cur[7]);
            w[2] = make_float4(cur[8], cur[9], cur[10], cur[11]);
            w[3] = make_float4(cur[12], cur[13], cur[14], cur[15]);
        }
        __syncthreads();
        float tt[HID];
        if (n < N) gl_eval(L, n, bufh, cur, woS, wfS, wtS, btS, tt);
        __syncthreads();
        if (n < N) {
            #pragma unroll
            for (int h = 0; h < HID; h++) prev2[h] = fmaf(2.f, tt[h], prev2[h]);  // prev2 := tmp
            float4* w = (float4*)(bufh + n * HID);
            w[0] = make_float4(prev2[0], prev2[1], prev2[2], prev2[3]);
            w[1] = make_float4(prev2[4], prev2[5], prev2[6], prev2[7]);
            w[2] = make_float4(prev2[8], prev2[9], prev2[10], prev2[11]);
            w[3] = make_float4(prev2[12], prev2[13], prev2[14], prev2[15]);
        }
        __syncthreads();
        float uu[HID];
        if (n < N) gl_eval(L, n, bufh, prev2, woS, wfS, wtS, btS, uu);
        __syncthreads();
        if (n < N) {
            #pragma unroll
            for (int h = 0; h < HID; h++) {
                float nc = cur[h] + 0.5f * (tt[h] + uu[h]);
                prev2[h] = cur[h];
                cur[h] = nc;
            }
        }
    }

    // ---- cstep + NL chain (pointwise; no barriers needed) ----
    if (n < N) {
        float s00[HID], s11[HID];
        #pragma unroll
        for (int h = 0; h < HID; h++) { s00[h] = cbS[h]; s11[h] = c1bS[h]; }
        #pragma unroll
        for (int h2 = 0; h2 < HID; h2++) {
            float a = prev2[h2], c2 = cur[h2];
            #pragma unroll
            for (int h = 0; h < HID; h++) {
                s00[h] = fmaf(a, cwS[h2 * HID + h], s00[h]);
                s11[h] = fmaf(c2, c1wS[h2 * HID + h], s11[h]);
            }
        }
        float* obase = out + ((size_t)b * N + n) * 10 * HID;
        float tt[HID], uu[HID], g[HID], p2[HID];
        nl_eval(s11, WiT, WgT, WoT, w2S, bS, tt);
        #pragma unroll
        for (int h = 0; h < HID; h++) s00[h] = fmaf(2.f, tt[h], s00[h]);
        nl_eval(s00, WiT, WgT, WoT, w2S, bS, uu);
        #pragma unroll
        for (int h = 0; h < HID; h++) {
            g[h] = cur[h] + 0.5f * (tt[h] + uu[h]);
            p2[h] = s11[h];
        }
        {
            float4* w = (float4*)obase;
            w[0] = make_float4(g[0], g[1], g[2], g[3]);
            w[1] = make_float4(g[4], g[5], g[6], g[7]);
            w[2] = make_float4(g[8], g[9], g[10], g[11]);
            w[3] = make_float4(g[12], g[13], g[14], g[15]);
        }
        for (int i = 1; i < 10; i++) {
            nl_eval(g, WiT, WgT, WoT, w2S, bS, tt);
            #pragma unroll
            for (int h = 0; h < HID; h++) p2[h] = fmaf(2.f, tt[h], p2[h]);  // p2 := tmp
            nl_eval(p2, WiT, WgT, WoT, w2S, bS, uu);
            #pragma unroll
            for (int h = 0; h < HID; h++) {
                float ng = g[h] + 0.5f * (tt[h] + uu[h]);
                p2[h] = g[h];
                g[h] = ng;
            }
            float4* w = (float4*)(obase + i * HID);
            w[0] = make_float4(g[0], g[1], g[2], g[3]);
            w[1] = make_float4(g[4], g[5], g[6], g[7]);
            w[2] = make_float4(g[8], g[9], g[10], g[11]);
            w[3] = make_float4(g[12], g[13], g[14], g[15]);
        }
    }
}

extern "C" void kernel_launch(void* const* d_in, const int* in_sizes, int n_in,
                              void* d_out, int out_size, void* d_ws, size_t ws_size,
                              hipStream_t stream) {
    const float* flow   = (const float*)d_in[0];
    const float* emb    = (const float*)d_in[1];
    const float* cheb_w = (const float*)d_in[2];
    const float* cheb_b = (const float*)d_in[3];
    const float* cou_w  = (const float*)d_in[4];
    const float* gl_out = (const float*)d_in[5];
    const float* gl_fk  = (const float*)d_in[6];
    const float* gl_tzw = (const float*)d_in[7];
    const float* gl_tzb = (const float*)d_in[8];
    const float* Wih    = (const float*)d_in[9];
    const float* lb     = (const float*)d_in[10];
    const float* w2     = (const float*)d_in[11];
    const float* c_w    = (const float*)d_in[12];
    const float* c_b    = (const float*)d_in[13];
    const float* c1_w   = (const float*)d_in[14];
    const float* c1_b   = (const float*)d_in[15];
    float* out = (float*)d_out;
    float* ws  = (float*)d_ws;

    size_t off = 0;
    float* polys = ws;       off += (size_t)KORD * N * N; off = (off + 255) & ~(size_t)255;
    float* G     = ws + off; off += (size_t)N * N;        off = (off + 255) & ~(size_t)255;
    float* dinv  = ws + off; off += 512;

    k_cosine<<<N, NT, 0, stream>>>(emb, G, dinv);
    k_laplacian<<<N, NT, 0, stream>>>(G, dinv, polys);
    for (int k = 2; k < KORD; k++)
        k_cheb_step<<<N, NT, 0, stream>>>(polys, k);
    k_chain<<<BATCH / 2, NTC, 0, stream>>>(flow, polys, cheb_w, cheb_b, cou_w,
                                           gl_out, gl_fk, gl_tzw, gl_tzb,
                                           Wih, lb, w2, c_w, c_b, c1_w, c1_b, out);
}